// Round 4
// baseline (411.351 us; speedup 1.0000x reference)
//
#include <hip/hip_runtime.h>

// Packed varlen causal GQA attention (flash-style), MI355X gfx950.
// Q [T,H,D] f32, K/V [T,G,D] f32, cu_seqlens [9] int32 -> O [T,H,D] f32.
// T=4096, H=16, G=4, D=128, SCALE=1/sqrt(128).
//
// Uses ONLY the HW-verified mfma_f32_16x16x32_bf16:
//   A[m=lane&15][k=quad*8+j], B[k=quad*8+j][n=lane&15],
//   C/D: row m = quad*4+reg, col n = lane&15.   (m89/m91, m118-m122)
// S^T = K*Q^T so masking/softmax reductions are 2 shuffles; P^T is moved
// from C/D layout to B-operand layout via a per-wave LDS round-trip (m120).
// Inputs f32 -> bf16 (RNE) in-register; output stored as f32.

#define T_TOK 4096
#define NH    16
#define NG    4
#define HD    128
#define NCU   9

typedef short          short8_t __attribute__((ext_vector_type(8)));
typedef float          float4_t __attribute__((ext_vector_type(4)));
typedef unsigned int   uint2_t  __attribute__((ext_vector_type(2)));
typedef unsigned short ushort;

static __device__ inline ushort f2bf(float x) {
    union { float f; unsigned u; } v; v.f = x;
    return (ushort)((v.u + 0x7fffu + ((v.u >> 16) & 1u)) >> 16);
}
static __device__ inline unsigned pack2(float a, float b) {
    return (unsigned)f2bf(a) | ((unsigned)f2bf(b) << 16);
}
static __device__ inline short8_t cvt8(float4_t lo, float4_t hi) {
    short8_t r;
    r[0] = (short)f2bf(lo[0]); r[1] = (short)f2bf(lo[1]);
    r[2] = (short)f2bf(lo[2]); r[3] = (short)f2bf(lo[3]);
    r[4] = (short)f2bf(hi[0]); r[5] = (short)f2bf(hi[1]);
    r[6] = (short)f2bf(hi[2]); r[7] = (short)f2bf(hi[3]);
    return r;
}

__global__ __launch_bounds__(256) void attn_fwd(
    const float* __restrict__ Q,
    const float* __restrict__ K,
    const float* __restrict__ V,
    const int*   __restrict__ cu,
    float*       __restrict__ O)
{
    __shared__ __align__(16) ushort pbuf[4][16][40];  // [wave][q][key 0..31, pad 40]

    const int qtile = blockIdx.x;        // 0..255
    const int g     = blockIdx.y;        // 0..3
    const int wave  = threadIdx.x >> 6;
    const int lane  = threadIdx.x & 63;
    const int h     = g * 4 + wave;      // query head; h//4 == g (jnp.repeat)
    const int col   = lane & 15;
    const int quad  = lane >> 4;

    const int qbase = qtile * 16;
    const int q     = qbase + col;

    // segment starts: max cu[j] <= q (per lane) and <= qbase (tile)
    int seg_start = 0, seg0 = 0;
    #pragma unroll
    for (int j = 1; j < NCU; ++j) {
        int cj = cu[j];
        if (cj <= q)     seg_start = cj;
        if (cj <= qbase) seg0      = cj;
    }
    const int k0 = seg0 & ~31;

    // Q fragment: B-operand of S^T = K*Q^T.
    // B[k=quad*8+j][n=col], dim = c*32 + quad*8 + j  -> 8 consecutive floats.
    short8_t qf[4];
    {
        const float* qp = Q + ((long)q * NH + h) * HD + quad * 8;
        #pragma unroll
        for (int c = 0; c < 4; ++c)
            qf[c] = cvt8(*(const float4_t*)(qp + c * 32),
                         *(const float4_t*)(qp + c * 32 + 4));
    }

    float4_t oacc[8];
    #pragma unroll
    for (int dt = 0; dt < 8; ++dt) oacc[dt] = (float4_t){0.f, 0.f, 0.f, 0.f};

    float m_run = -10000.0f;
    float l_run = 0.0f;
    const float c_scale = 0.08838834764831845f * 1.4426950408889634f; // SCALE*log2e

    for (int kb = k0; kb <= qbase + 15; kb += 32) {
        // ---- S^T tiles (16 keys x 16 q), two per 32-key block ----
        float4_t st[2];
        #pragma unroll
        for (int t = 0; t < 2; ++t) {
            int krow = kb + 16 * t + col;          // A: m = col = key row
            if (krow > T_TOK - 1) krow = T_TOK - 1; // clamp (masked anyway)
            const float* kp = K + ((long)krow * NG + g) * HD + quad * 8;
            float4_t acc = (float4_t){0.f, 0.f, 0.f, 0.f};
            #pragma unroll
            for (int c = 0; c < 4; ++c) {
                short8_t kf = cvt8(*(const float4_t*)(kp + c * 32),
                                   *(const float4_t*)(kp + c * 32 + 4));
                acc = __builtin_amdgcn_mfma_f32_16x16x32_bf16(kf, qf[c], acc, 0, 0, 0);
            }
            st[t] = acc;   // st[t][r] = S^T[key = kb+16t+quad*4+r][q = qbase+col]
        }

        // ---- mask + online softmax over 32 keys (log2 domain) ----
        float tv[8];
        #pragma unroll
        for (int t = 0; t < 2; ++t)
            #pragma unroll
            for (int r = 0; r < 4; ++r) {
                int key = kb + 16 * t + quad * 4 + r;
                bool valid = (key <= q) && (key >= seg_start);
                tv[t * 4 + r] = valid ? st[t][r] * c_scale : -30000.0f;
            }
        float tmax = tv[0];
        #pragma unroll
        for (int i = 1; i < 8; ++i) tmax = fmaxf(tmax, tv[i]);
        tmax = fmaxf(tmax, __shfl_xor(tmax, 16));
        tmax = fmaxf(tmax, __shfl_xor(tmax, 32));
        const float m_new = fmaxf(m_run, tmax);
        const float alpha = __builtin_exp2f(m_run - m_new);
        float p[8], ps = 0.f;
        #pragma unroll
        for (int i = 0; i < 8; ++i) { p[i] = __builtin_exp2f(tv[i] - m_new); ps += p[i]; }
        ps += __shfl_xor(ps, 16);
        ps += __shfl_xor(ps, 32);
        l_run = l_run * alpha + ps;
        m_run = m_new;
        #pragma unroll
        for (int dt = 0; dt < 8; ++dt) oacc[dt] *= alpha;

        // ---- P^T: C/D layout -> LDS -> B-operand layout (m120 pattern) ----
        // write P^T[q=col][key = 16t + quad*4 + r]
        {
            uint2_t w0; w0.x = pack2(p[0], p[1]); w0.y = pack2(p[2], p[3]);
            uint2_t w1; w1.x = pack2(p[4], p[5]); w1.y = pack2(p[6], p[7]);
            *(uint2_t*)&pbuf[wave][col][quad * 4]      = w0;
            *(uint2_t*)&pbuf[wave][col][16 + quad * 4] = w1;
        }
        // read B[k = key = quad*8+j][n = q = col]
        short8_t pf = *(const short8_t*)&pbuf[wave][col][quad * 8];

        // ---- O^T += V^T * P^T ----
        // A = V^T: A[m = dim-in-tile = col][k = key = quad*8+j]
        const float* vp[8];
        #pragma unroll
        for (int j = 0; j < 8; ++j) {
            int tk = kb + quad * 8 + j;
            if (tk > T_TOK - 1) tk = T_TOK - 1;   // clamp (P==0 there)
            vp[j] = V + ((long)tk * NG + g) * HD + col;
        }
        #pragma unroll
        for (int dt = 0; dt < 8; ++dt) {
            short8_t vf;
            #pragma unroll
            for (int j = 0; j < 8; ++j) vf[j] = (short)f2bf(vp[j][dt * 16]);
            oacc[dt] = __builtin_amdgcn_mfma_f32_16x16x32_bf16(vf, pf, oacc[dt], 0, 0, 0);
        }
    }

    // ---- epilogue: O[q][h][dim = dt*16 + quad*4 + r] = oacc/l  (f32 out) ----
    const float inv_l = 1.0f / l_run;
    float* op = O + ((long)q * NH + h) * HD + quad * 4;
    #pragma unroll
    for (int dt = 0; dt < 8; ++dt) {
        float4_t ov;
        #pragma unroll
        for (int r = 0; r < 4; ++r) ov[r] = oacc[dt][r] * inv_l;
        *(float4_t*)(op + dt * 16) = ov;
    }
}

extern "C" void kernel_launch(void* const* d_in, const int* in_sizes, int n_in,
                              void* d_out, int out_size, void* d_ws, size_t ws_size,
                              hipStream_t stream) {
    const float* Q  = (const float*)d_in[0];
    const float* K  = (const float*)d_in[1];
    const float* V  = (const float*)d_in[2];
    const int*   cu = (const int*)d_in[3];
    float*       O  = (float*)d_out;
    dim3 grid(T_TOK / 16, NG);
    attn_fwd<<<grid, 256, 0, stream>>>(Q, K, V, cu, O);
}

// Round 5
// 273.599 us; speedup vs baseline: 1.5035x; 1.5035x over previous
//
#include <hip/hip_runtime.h>
#include <hip/hip_bf16.h>

// Packed varlen causal GQA attention (flash-style), MI355X gfx950.
// Q [T,H,D] f32, K/V [T,G,D] f32, cu_seqlens [9] int32 -> O [T,H,D] f32.
// T=4096, H=16, G=4, D=128, SCALE=1/sqrt(128).
//
// R5: cooperative LDS staging of K (natural, bf16) and V (transposed, bf16)
// per 32-key block -- kills the 64-scalar-load V gather and the 4x duplicate
// K loads across waves. MFMA fragments now come from ds_read_b128.
// MFMA layouts (HW-verified m89/m91/m118-m122), 16x16x32_bf16:
//   A[m=lane&15][k=quad*8+j], B[k=quad*8+j][n=lane&15],
//   C/D: row m = quad*4+reg, col n = lane&15.

#define T_TOK 4096
#define NH    16
#define NG    4
#define HD    128
#define NCU   9

typedef short          short8_t __attribute__((ext_vector_type(8)));
typedef float          float4_t __attribute__((ext_vector_type(4)));
typedef unsigned int   uint2_t  __attribute__((ext_vector_type(2)));
typedef unsigned short ushort;

static __device__ inline unsigned pack2(float a, float b) {
    __hip_bfloat162 h = __float22bfloat162_rn(make_float2(a, b));
    union { __hip_bfloat162 h; unsigned u; } c; c.h = h;
    return c.u;
}
static __device__ inline short8_t cvt8(float4_t lo, float4_t hi) {
    union { unsigned u[4]; short8_t s; } r;
    r.u[0] = pack2(lo[0], lo[1]); r.u[1] = pack2(lo[2], lo[3]);
    r.u[2] = pack2(hi[0], hi[1]); r.u[3] = pack2(hi[2], hi[3]);
    return r.s;
}

__global__ __launch_bounds__(256) void attn_fwd(
    const float* __restrict__ Q,
    const float* __restrict__ K,
    const float* __restrict__ V,
    const int*   __restrict__ cu,
    float*       __restrict__ O)
{
    // K tile: [key 0..31][dim 0..127], row pad 128->136 (2-way max on reads)
    __shared__ __align__(16) ushort Ks[32][136];
    // V^T tile: [dim 0..127][key 0..31], row pad 32->40 (80B rows, 16B-aligned)
    __shared__ __align__(16) ushort Vt[128][40];
    // P^T round-trip buffer, per wave
    __shared__ __align__(16) ushort pbuf[4][16][40];

    const int qtile = (int)gridDim.x - 1 - (int)blockIdx.x; // big tiles first
    const int g     = blockIdx.y;
    const int tid   = threadIdx.x;
    const int wave  = tid >> 6;
    const int lane  = tid & 63;
    const int h     = g * 4 + wave;      // query head; h//4 == g (jnp.repeat)
    const int col   = lane & 15;
    const int quad  = lane >> 4;

    const int qbase = qtile * 16;
    const int q     = qbase + col;

    // segment starts: max cu[j] <= q (lane) and <= qbase (tile; block-uniform)
    int seg_start = 0, seg0 = 0;
    #pragma unroll
    for (int j = 1; j < NCU; ++j) {
        int cj = cu[j];
        if (cj <= q)     seg_start = cj;
        if (cj <= qbase) seg0      = cj;
    }
    const int k0 = seg0 & ~31;

    // Q fragment: B-operand of S^T = K*Q^T. dim = c*32 + quad*8 + j.
    short8_t qf[4];
    {
        const float* qp = Q + ((long)q * NH + h) * HD + quad * 8;
        #pragma unroll
        for (int c = 0; c < 4; ++c)
            qf[c] = cvt8(*(const float4_t*)(qp + c * 32),
                         *(const float4_t*)(qp + c * 32 + 4));
    }

    float4_t oacc[8];
    #pragma unroll
    for (int dt = 0; dt < 8; ++dt) oacc[dt] = (float4_t){0.f, 0.f, 0.f, 0.f};

    float m_run = -10000.0f;
    float l_run = 0.0f;
    const float c_scale = 0.08838834764831845f * 1.4426950408889634f; // SCALE*log2e

    for (int kb = k0; kb <= qbase + 15; kb += 32) {
        __syncthreads();   // previous iter's LDS reads complete

        // ---- cooperative staging: K[32x128] -> Ks (bf16) ----
        {
            int ki = tid >> 3;            // key-in-tile
            int ch = (tid & 7) * 16;      // dim chunk
            int key = kb + ki; if (key > T_TOK - 1) key = T_TOK - 1;
            const float* kp = K + ((long)key * NG + g) * HD + ch;
            short8_t lo = cvt8(*(const float4_t*)kp, *(const float4_t*)(kp + 4));
            short8_t hi = cvt8(*(const float4_t*)(kp + 8), *(const float4_t*)(kp + 12));
            *(short8_t*)&Ks[ki][ch]     = lo;
            *(short8_t*)&Ks[ki][ch + 8] = hi;
        }
        // ---- cooperative staging: V[32x128] -> Vt (bf16, transposed) ----
        {
            int kp2 = (tid & 15) * 2;     // key pair
            int dc  = (tid >> 4) * 8;     // dim chunk
            int key0 = kb + kp2;     if (key0 > T_TOK - 1) key0 = T_TOK - 1;
            int key1 = kb + kp2 + 1; if (key1 > T_TOK - 1) key1 = T_TOK - 1;
            const float* v0 = V + ((long)key0 * NG + g) * HD + dc;
            const float* v1 = V + ((long)key1 * NG + g) * HD + dc;
            float4_t a0 = *(const float4_t*)v0;
            float4_t a1 = *(const float4_t*)(v0 + 4);
            float4_t b0 = *(const float4_t*)v1;
            float4_t b1 = *(const float4_t*)(v1 + 4);
            #pragma unroll
            for (int d = 0; d < 4; ++d) {
                *(unsigned*)&Vt[dc + d][kp2]     = pack2(a0[d], b0[d]);
                *(unsigned*)&Vt[dc + 4 + d][kp2] = pack2(a1[d], b1[d]);
            }
        }
        __syncthreads();

        // ---- S^T tiles (16 keys x 16 q), two per 32-key block ----
        float4_t st[2];
        #pragma unroll
        for (int t = 0; t < 2; ++t) {
            float4_t acc = (float4_t){0.f, 0.f, 0.f, 0.f};
            #pragma unroll
            for (int c = 0; c < 4; ++c) {
                short8_t kf = *(const short8_t*)&Ks[16 * t + col][c * 32 + quad * 8];
                acc = __builtin_amdgcn_mfma_f32_16x16x32_bf16(kf, qf[c], acc, 0, 0, 0);
            }
            st[t] = acc;   // st[t][r] = S^T[key = kb+16t+quad*4+r][q = qbase+col]
        }

        // ---- mask + online softmax over 32 keys (log2 domain) ----
        float tv[8];
        #pragma unroll
        for (int t = 0; t < 2; ++t)
            #pragma unroll
            for (int r = 0; r < 4; ++r) {
                int key = kb + 16 * t + quad * 4 + r;
                bool valid = (key <= q) && (key >= seg_start);
                tv[t * 4 + r] = valid ? st[t][r] * c_scale : -30000.0f;
            }
        float tmax = tv[0];
        #pragma unroll
        for (int i = 1; i < 8; ++i) tmax = fmaxf(tmax, tv[i]);
        tmax = fmaxf(tmax, __shfl_xor(tmax, 16));
        tmax = fmaxf(tmax, __shfl_xor(tmax, 32));
        const float m_new = fmaxf(m_run, tmax);
        const float alpha = __builtin_exp2f(m_run - m_new);
        float p[8], ps = 0.f;
        #pragma unroll
        for (int i = 0; i < 8; ++i) { p[i] = __builtin_exp2f(tv[i] - m_new); ps += p[i]; }
        ps += __shfl_xor(ps, 16);
        ps += __shfl_xor(ps, 32);
        l_run = l_run * alpha + ps;
        m_run = m_new;
        #pragma unroll
        for (int dt = 0; dt < 8; ++dt) oacc[dt] *= alpha;

        // ---- P^T: C/D layout -> LDS -> B-operand layout (m120 pattern) ----
        {
            uint2_t w0; w0.x = pack2(p[0], p[1]); w0.y = pack2(p[2], p[3]);
            uint2_t w1; w1.x = pack2(p[4], p[5]); w1.y = pack2(p[6], p[7]);
            *(uint2_t*)&pbuf[wave][col][quad * 4]      = w0;
            *(uint2_t*)&pbuf[wave][col][16 + quad * 4] = w1;
        }
        short8_t pf = *(const short8_t*)&pbuf[wave][col][quad * 8];

        // ---- O^T += V^T * P^T : A = V^T from Vt, 16B contiguous ----
        #pragma unroll
        for (int dt = 0; dt < 8; ++dt) {
            short8_t vf = *(const short8_t*)&Vt[dt * 16 + col][quad * 8];
            oacc[dt] = __builtin_amdgcn_mfma_f32_16x16x32_bf16(vf, pf, oacc[dt], 0, 0, 0);
        }
    }

    // ---- epilogue: O[q][h][dim = dt*16 + quad*4 + r] = oacc/l  (f32 out) ----
    const float inv_l = 1.0f / l_run;
    float* op = O + ((long)q * NH + h) * HD + quad * 4;
    #pragma unroll
    for (int dt = 0; dt < 8; ++dt) {
        float4_t ov;
        #pragma unroll
        for (int r = 0; r < 4; ++r) ov[r] = oacc[dt][r] * inv_l;
        *(float4_t*)(op + dt * 16) = ov;
    }
}

extern "C" void kernel_launch(void* const* d_in, const int* in_sizes, int n_in,
                              void* d_out, int out_size, void* d_ws, size_t ws_size,
                              hipStream_t stream) {
    const float* Q  = (const float*)d_in[0];
    const float* K  = (const float*)d_in[1];
    const float* V  = (const float*)d_in[2];
    const int*   cu = (const int*)d_in[3];
    float*       O  = (float*)d_out;
    dim3 grid(T_TOK / 16, NG);
    attn_fwd<<<grid, 256, 0, stream>>>(Q, K, V, cu, O);
}

// Round 6
// 247.131 us; speedup vs baseline: 1.6645x; 1.1071x over previous
//
#include <hip/hip_runtime.h>
#include <hip/hip_bf16.h>

// Packed varlen causal GQA attention (flash-style), MI355X gfx950.
// Q [T,H,D] f32, K/V [T,G,D] f32, cu_seqlens [9] int32 -> O [T,H,D] f32.
// T=4096, H=16, G=4, D=128, SCALE=1/sqrt(128).
//
// R6: (a) 2 q-tiles (32 q rows) per wave -- every K/V LDS fragment feeds 2
// MFMAs (32 MFMA : 18 ds_read_b128, was 16:17); staging amortized over 2x
// work. (b) software pipeline: next iter's K/V global loads issued into
// registers right after the LDS-ready barrier, stored to LDS next iter --
// ~8 VMEM in flight across the whole compute section.
// MFMA layouts (HW-verified m89/m91/m118-m122), 16x16x32_bf16:
//   A[m=lane&15][k=quad*8+j], B[k=quad*8+j][n=lane&15],
//   C/D: row m = quad*4+reg, col n = lane&15.

#define T_TOK 4096
#define NH    16
#define NG    4
#define HD    128
#define NCU   9

typedef short          short8_t __attribute__((ext_vector_type(8)));
typedef float          float4_t __attribute__((ext_vector_type(4)));
typedef unsigned int   uint2_t  __attribute__((ext_vector_type(2)));
typedef unsigned short ushort;

static __device__ inline unsigned pack2(float a, float b) {
    __hip_bfloat162 h = __float22bfloat162_rn(make_float2(a, b));
    union { __hip_bfloat162 h; unsigned u; } c; c.h = h;
    return c.u;
}
static __device__ inline short8_t cvt8(float4_t lo, float4_t hi) {
    union { unsigned u[4]; short8_t s; } r;
    r.u[0] = pack2(lo[0], lo[1]); r.u[1] = pack2(lo[2], lo[3]);
    r.u[2] = pack2(hi[0], hi[1]); r.u[3] = pack2(hi[2], hi[3]);
    return r.s;
}

__global__ __launch_bounds__(256) void attn_fwd(
    const float* __restrict__ Q,
    const float* __restrict__ K,
    const float* __restrict__ V,
    const int*   __restrict__ cu,
    float*       __restrict__ O)
{
    // K tile: [key 0..31][dim 0..127], row pad 128->136
    __shared__ __align__(16) ushort Ks[32][136];
    // V^T tile: [dim 0..127][key 0..31], row pad 32->40
    __shared__ __align__(16) ushort Vt[128][40];
    // P^T round-trip buffer, per wave per q-tile
    __shared__ __align__(16) ushort pbuf[4][2][16][40];

    const int qtile = (int)gridDim.x - 1 - (int)blockIdx.x; // big tiles first
    const int g     = blockIdx.y;
    const int tid   = threadIdx.x;
    const int wave  = tid >> 6;
    const int lane  = tid & 63;
    const int h     = g * 4 + wave;      // query head; h//4 == g (jnp.repeat)
    const int col   = lane & 15;
    const int quad  = lane >> 4;

    const int qbase = qtile * 32;        // 32 q rows per block
    const int qq[2] = { qbase + col, qbase + 16 + col };

    // segment starts: per-lane per-tile, and block-uniform for k0
    int seg_start[2] = {0, 0}, seg0 = 0;
    #pragma unroll
    for (int j = 1; j < NCU; ++j) {
        int cj = cu[j];
        if (cj <= qq[0])  seg_start[0] = cj;
        if (cj <= qq[1])  seg_start[1] = cj;
        if (cj <= qbase)  seg0         = cj;
    }
    const int k0 = seg0 & ~31;

    // Q fragments (B-operand of S^T = K*Q^T), 2 tiles. dim = c*32+quad*8+j.
    short8_t qf[2][4];
    #pragma unroll
    for (int tt = 0; tt < 2; ++tt) {
        const float* qp = Q + ((long)qq[tt] * NH + h) * HD + quad * 8;
        #pragma unroll
        for (int c = 0; c < 4; ++c)
            qf[tt][c] = cvt8(*(const float4_t*)(qp + c * 32),
                             *(const float4_t*)(qp + c * 32 + 4));
    }

    float4_t oacc[2][8];
    #pragma unroll
    for (int tt = 0; tt < 2; ++tt)
        #pragma unroll
        for (int dt = 0; dt < 8; ++dt) oacc[tt][dt] = (float4_t){0.f, 0.f, 0.f, 0.f};

    float m_run[2] = {-10000.0f, -10000.0f};
    float l_run[2] = {0.0f, 0.0f};
    const float c_scale = 0.08838834764831845f * 1.4426950408889634f; // SCALE*log2e

    // staging thread mapping (block-cooperative, 32 keys x 128 dims)
    const int ki  = tid >> 3;            // K: key-in-tile
    const int ch  = (tid & 7) * 16;      // K: dim chunk
    const int kp2 = (tid & 15) * 2;      // V: key pair
    const int dc  = (tid >> 4) * 8;      // V: dim chunk

    float4_t kreg[4], vreg[4];
    {
        int key = k0 + ki; if (key > T_TOK - 1) key = T_TOK - 1;
        const float* kp = K + ((long)key * NG + g) * HD + ch;
        kreg[0] = *(const float4_t*)kp;       kreg[1] = *(const float4_t*)(kp + 4);
        kreg[2] = *(const float4_t*)(kp + 8); kreg[3] = *(const float4_t*)(kp + 12);
        int key0 = k0 + kp2;     if (key0 > T_TOK - 1) key0 = T_TOK - 1;
        int key1 = k0 + kp2 + 1; if (key1 > T_TOK - 1) key1 = T_TOK - 1;
        const float* v0 = V + ((long)key0 * NG + g) * HD + dc;
        const float* v1 = V + ((long)key1 * NG + g) * HD + dc;
        vreg[0] = *(const float4_t*)v0; vreg[1] = *(const float4_t*)(v0 + 4);
        vreg[2] = *(const float4_t*)v1; vreg[3] = *(const float4_t*)(v1 + 4);
    }

    for (int kb = k0; kb <= qbase + 31; kb += 32) {
        __syncthreads();   // previous iter's LDS reads complete

        // ---- write prefetched K/V regs -> LDS (bf16) ----
        *(short8_t*)&Ks[ki][ch]     = cvt8(kreg[0], kreg[1]);
        *(short8_t*)&Ks[ki][ch + 8] = cvt8(kreg[2], kreg[3]);
        #pragma unroll
        for (int d = 0; d < 4; ++d) {
            *(unsigned*)&Vt[dc + d][kp2]     = pack2(vreg[0][d], vreg[2][d]);
            *(unsigned*)&Vt[dc + 4 + d][kp2] = pack2(vreg[1][d], vreg[3][d]);
        }
        __syncthreads();

        // ---- prefetch next 32-key block (in flight during compute) ----
        {
            int nb = kb + 32;
            int key = nb + ki; if (key > T_TOK - 1) key = T_TOK - 1;
            const float* kp = K + ((long)key * NG + g) * HD + ch;
            kreg[0] = *(const float4_t*)kp;       kreg[1] = *(const float4_t*)(kp + 4);
            kreg[2] = *(const float4_t*)(kp + 8); kreg[3] = *(const float4_t*)(kp + 12);
            int key0 = nb + kp2;     if (key0 > T_TOK - 1) key0 = T_TOK - 1;
            int key1 = nb + kp2 + 1; if (key1 > T_TOK - 1) key1 = T_TOK - 1;
            const float* v0 = V + ((long)key0 * NG + g) * HD + dc;
            const float* v1 = V + ((long)key1 * NG + g) * HD + dc;
            vreg[0] = *(const float4_t*)v0; vreg[1] = *(const float4_t*)(v0 + 4);
            vreg[2] = *(const float4_t*)v1; vreg[3] = *(const float4_t*)(v1 + 4);
        }

        // ---- S^T tiles: 8 K-frag reads feed 16 MFMAs (2 q-tiles) ----
        float4_t st[2][2];
        #pragma unroll
        for (int tt = 0; tt < 2; ++tt)
            #pragma unroll
            for (int t = 0; t < 2; ++t) st[tt][t] = (float4_t){0.f, 0.f, 0.f, 0.f};
        #pragma unroll
        for (int c = 0; c < 4; ++c) {
            short8_t kf0 = *(const short8_t*)&Ks[col][c * 32 + quad * 8];
            short8_t kf1 = *(const short8_t*)&Ks[16 + col][c * 32 + quad * 8];
            st[0][0] = __builtin_amdgcn_mfma_f32_16x16x32_bf16(kf0, qf[0][c], st[0][0], 0, 0, 0);
            st[0][1] = __builtin_amdgcn_mfma_f32_16x16x32_bf16(kf1, qf[0][c], st[0][1], 0, 0, 0);
            st[1][0] = __builtin_amdgcn_mfma_f32_16x16x32_bf16(kf0, qf[1][c], st[1][0], 0, 0, 0);
            st[1][1] = __builtin_amdgcn_mfma_f32_16x16x32_bf16(kf1, qf[1][c], st[1][1], 0, 0, 0);
        }

        // ---- mask + online softmax per q-tile (log2 domain) ----
        #pragma unroll
        for (int tt = 0; tt < 2; ++tt) {
            float tv[8];
            #pragma unroll
            for (int t = 0; t < 2; ++t)
                #pragma unroll
                for (int r = 0; r < 4; ++r) {
                    int key = kb + 16 * t + quad * 4 + r;
                    bool valid = (key <= qq[tt]) && (key >= seg_start[tt]);
                    tv[t * 4 + r] = valid ? st[tt][t][r] * c_scale : -30000.0f;
                }
            float tmax = tv[0];
            #pragma unroll
            for (int i = 1; i < 8; ++i) tmax = fmaxf(tmax, tv[i]);
            tmax = fmaxf(tmax, __shfl_xor(tmax, 16));
            tmax = fmaxf(tmax, __shfl_xor(tmax, 32));
            const float m_new = fmaxf(m_run[tt], tmax);
            const float alpha = __builtin_exp2f(m_run[tt] - m_new);
            float p[8], ps = 0.f;
            #pragma unroll
            for (int i = 0; i < 8; ++i) { p[i] = __builtin_exp2f(tv[i] - m_new); ps += p[i]; }
            ps += __shfl_xor(ps, 16);
            ps += __shfl_xor(ps, 32);
            l_run[tt] = l_run[tt] * alpha + ps;
            m_run[tt] = m_new;
            #pragma unroll
            for (int dt = 0; dt < 8; ++dt) oacc[tt][dt] *= alpha;

            uint2_t w0; w0.x = pack2(p[0], p[1]); w0.y = pack2(p[2], p[3]);
            uint2_t w1; w1.x = pack2(p[4], p[5]); w1.y = pack2(p[6], p[7]);
            *(uint2_t*)&pbuf[wave][tt][col][quad * 4]      = w0;
            *(uint2_t*)&pbuf[wave][tt][col][16 + quad * 4] = w1;
        }
        short8_t pf0 = *(const short8_t*)&pbuf[wave][0][col][quad * 8];
        short8_t pf1 = *(const short8_t*)&pbuf[wave][1][col][quad * 8];

        // ---- O^T += V^T * P^T : 8 V-frag reads feed 16 MFMAs ----
        #pragma unroll
        for (int dt = 0; dt < 8; ++dt) {
            short8_t vf = *(const short8_t*)&Vt[dt * 16 + col][quad * 8];
            oacc[0][dt] = __builtin_amdgcn_mfma_f32_16x16x32_bf16(vf, pf0, oacc[0][dt], 0, 0, 0);
            oacc[1][dt] = __builtin_amdgcn_mfma_f32_16x16x32_bf16(vf, pf1, oacc[1][dt], 0, 0, 0);
        }
    }

    // ---- epilogue: O[q][h][dim = dt*16 + quad*4 + r] = oacc/l  (f32) ----
    #pragma unroll
    for (int tt = 0; tt < 2; ++tt) {
        const float inv_l = 1.0f / l_run[tt];
        float* op = O + ((long)qq[tt] * NH + h) * HD + quad * 4;
        #pragma unroll
        for (int dt = 0; dt < 8; ++dt) {
            float4_t ov;
            #pragma unroll
            for (int r = 0; r < 4; ++r) ov[r] = oacc[tt][dt][r] * inv_l;
            *(float4_t*)(op + dt * 16) = ov;
        }
    }
}

extern "C" void kernel_launch(void* const* d_in, const int* in_sizes, int n_in,
                              void* d_out, int out_size, void* d_ws, size_t ws_size,
                              hipStream_t stream) {
    const float* Q  = (const float*)d_in[0];
    const float* K  = (const float*)d_in[1];
    const float* V  = (const float*)d_in[2];
    const int*   cu = (const int*)d_in[3];
    float*       O  = (float*)d_out;
    dim3 grid(T_TOK / 32, NG);
    attn_fwd<<<grid, 256, 0, stream>>>(Q, K, V, cu, O);
}